// Round 4
// baseline (362.524 us; speedup 1.0000x reference)
//
#include <hip/hip_runtime.h>

// SSIM fused kernel, round 4: single-wave workgroups (block = 64 = 1 wave).
// B=16, C=3, H=W=768, 11-tap separable Gaussian, VALID -> 758x758; out = per-batch mean [16].
//
// Changes vs R3:
//  - 64-col tiles, 1 wave/block: s_barrier elided (flat_work_group_size 64), so the
//    2-barriers/macro-iter coupling that pinned VALUBusy at ~59% is gone; all resident
//    waves independent.
//  - LDS handoff 4 KB/block, [row][col][field] layout -> stage B = 1 ds_read_b128/row.
//  - waves_per_eu(4,8): 128-VGPR budget (live ~115), no scratch; residency VGPR-limited.
//  - Stage A squares in place (peak pressure ~115 vs R3's ~147).

#define H_IMG 768
#define W_IMG 768
#define OH 758
#define OW_TOT 758
#define OWS 64     // output cols per strip (= wave width)
#define NSTRIP 12  // ceil(758/64)
#define NSEG 16    // vertical segments

__global__ void ssim_zero_out(float* __restrict__ out) {
    if (threadIdx.x < 16) out[threadIdx.x] = 0.0f;
}

__attribute__((amdgpu_flat_work_group_size(64, 64), amdgpu_waves_per_eu(4, 8)))
__global__ void ssim_fused(const float* __restrict__ X, const float* __restrict__ Y,
                           const float* __restrict__ Wg, float* __restrict__ out) {
    const float C1 = 1e-4f, C2 = 9e-4f, EPS = 1e-8f;
    const float INV_COUNT = 1.0f / (3.0f * 758.0f * 758.0f);

    const int t = threadIdx.x;
    int bx = blockIdx.x;
    const int strip = bx % NSTRIP; bx /= NSTRIP;
    const int seg = bx & (NSEG - 1); bx >>= 4;
    const int ch = bx % 3;
    const int b  = bx / 3;

    const int R0 = (OH * seg) / NSEG;
    const int Rend = (OH * (seg + 1)) / NSEG;
    const int hseg = Rend - R0;
    const int c0 = strip * OWS;

    const float* Xi = X + (size_t)(b * 3 + ch) * (H_IMG * W_IMG);
    const float* Yi = Y + (size_t)(b * 3 + ch) * (H_IMG * W_IMG);

    float w[11];
#pragma unroll
    for (int k = 0; k < 11; ++k) w[k] = Wg[k];

    // LDS handoff: [4 stage-A rows][64 cols][4 fields] -> stage B reads b128/col.
    __shared__ __align__(16) float hb[4][OWS][4];   // 4 KB

    // Stage A mapping: 4 rows x 16 col-groups (4 cols each).
    const int sA = t >> 4;
    const int cg = t & 15;
    const int colbase = c0 + 4 * cg;
    const int k0 = min(colbase,      W_IMG - 4);
    const int k1 = min(colbase + 4,  W_IMG - 4);
    const int k2 = min(colbase + 8,  W_IMG - 4);
    const int k3 = min(colbase + 12, W_IMG - 2);

    // Stage B: ring-16 per field {mu_x, mu_y, x^2+y^2, x*y}; slot of rel h-row r = r & 15.
    float rg[4][16];
#pragma unroll
    for (int f = 0; f < 4; ++f)
#pragma unroll
        for (int j = 0; j < 16; ++j) rg[f][j] = 0.0f;

    const bool colok = (c0 + t) < OW_TOT;
    float local = 0.0f;
    const int M = (hseg + 13) >> 2;   // macro-iters of 4 input rows

    for (int mb = 0; mb < M; mb += 4) {
#pragma unroll
        for (int p = 0; p < 4; ++p) {
            const int m = mb + p;
            if (m < M) {
                // ---------------- Stage A: horizontal blur ----------------
                {
                    int r = R0 + 4 * m + sA;
                    r = min(r, H_IMG - 1);
                    const float* xr = Xi + (size_t)r * W_IMG;
                    const float* yr = Yi + (size_t)r * W_IMG;
                    float4 xa = *(const float4*)(xr + k0);
                    float4 xb = *(const float4*)(xr + k1);
                    float4 xc = *(const float4*)(xr + k2);
                    float2 xd = *(const float2*)(xr + k3);
                    float4 ya = *(const float4*)(yr + k0);
                    float4 yb = *(const float4*)(yr + k1);
                    float4 yc = *(const float4*)(yr + k2);
                    float2 yd = *(const float2*)(yr + k3);
                    float xv[14] = {xa.x, xa.y, xa.z, xa.w, xb.x, xb.y, xb.z, xb.w,
                                    xc.x, xc.y, xc.z, xc.w, xd.x, xd.y};
                    float yv[14] = {ya.x, ya.y, ya.z, ya.w, yb.x, yb.y, yb.z, yb.w,
                                    yc.x, yc.y, yc.z, yc.w, yd.x, yd.y};
                    float pv[14];
#pragma unroll
                    for (int j = 0; j < 14; ++j) pv[j] = xv[j] * yv[j];

                    float h0[4], h1[4], h3[4];
#pragma unroll
                    for (int cc = 0; cc < 4; ++cc) {
                        float a0 = 0.f, a1 = 0.f, a3 = 0.f;
#pragma unroll
                        for (int k = 0; k < 11; ++k) {
                            a0 = fmaf(w[k], xv[cc + k], a0);
                            a1 = fmaf(w[k], yv[cc + k], a1);
                            a3 = fmaf(w[k], pv[cc + k], a3);
                        }
                        h0[cc] = a0; h1[cc] = a1; h3[cc] = a3;
                    }
                    // Squares in place: xv <- x^2 + y^2 (yv dead after).
#pragma unroll
                    for (int j = 0; j < 14; ++j)
                        xv[j] = fmaf(xv[j], xv[j], yv[j] * yv[j]);
                    float h2[4];
#pragma unroll
                    for (int cc = 0; cc < 4; ++cc) {
                        float a2 = 0.f;
#pragma unroll
                        for (int k = 0; k < 11; ++k)
                            a2 = fmaf(w[k], xv[cc + k], a2);
                        h2[cc] = a2;
                    }
#pragma unroll
                    for (int cc = 0; cc < 4; ++cc) {
                        *(float4*)&hb[sA][4 * cg + cc][0] =
                            make_float4(h0[cc], h1[cc], h2[cc], h3[cc]);
                    }
                }
                __syncthreads();   // single wave: compiles to waitcnt only

                // ---------------- Stage B: insert + vertical blur + SSIM ----------------
                {
#pragma unroll
                    for (int s2 = 0; s2 < 4; ++s2) {
                        float4 hv = *(const float4*)&hb[s2][t][0];
                        const int sl = (4 * p + s2) & 15;
                        rg[0][sl] = hv.x; rg[1][sl] = hv.y;
                        rg[2][sl] = hv.z; rg[3][sl] = hv.w;
                    }
#pragma unroll
                    for (int s2 = 0; s2 < 4; ++s2) {
                        const int orel = 4 * m - 10 + s2;
                        float a0 = 0.f, a1 = 0.f, a2 = 0.f, a3 = 0.f;
#pragma unroll
                        for (int k = 0; k < 11; ++k) {
                            const int sl = (4 * p + s2 + k + 6) & 15;
                            a0 = fmaf(w[k], rg[0][sl], a0);
                            a1 = fmaf(w[k], rg[1][sl], a1);
                            a2 = fmaf(w[k], rg[2][sl], a2);
                            a3 = fmaf(w[k], rg[3][sl], a3);
                        }
                        const float mux2 = a0 * a0;
                        const float muy2 = a1 * a1;
                        const float mxy  = a0 * a1;
                        const float sigsum = a2 - mux2 - muy2;  // sigma_x + sigma_y
                        const float sxy    = a3 - mxy;
                        const float num = (2.0f * mxy + C1) * (2.0f * sxy + C2);
                        const float den = (mux2 + muy2 + C1 + EPS) * (sigsum + C2 + EPS);
                        const float v = fmaxf(__fdividef(num, den), 0.0f);
                        if (colok && (orel >= 0) && (orel < hseg)) local += v;
                    }
                }
                __syncthreads();
            }
        }
    }

    // ---------------- wave reduction + atomic ----------------
    float v = local;
#pragma unroll
    for (int off = 32; off > 0; off >>= 1) v += __shfl_down(v, off, 64);
    if (t == 0) atomicAdd(&out[b], v * INV_COUNT);
}

extern "C" void kernel_launch(void* const* d_in, const int* in_sizes, int n_in,
                              void* d_out, int out_size, void* d_ws, size_t ws_size,
                              hipStream_t stream) {
    const float* X  = (const float*)d_in[0];
    const float* Y  = (const float*)d_in[1];
    const float* Wg = (const float*)d_in[2];
    float* out = (float*)d_out;

    hipLaunchKernelGGL(ssim_zero_out, dim3(1), dim3(64), 0, stream, out);
    hipLaunchKernelGGL(ssim_fused, dim3(48 * NSEG * NSTRIP), dim3(64), 0, stream,
                       X, Y, Wg, out);
}

// Round 5
// 283.250 us; speedup vs baseline: 1.2799x; 1.2799x over previous
//
#include <hip/hip_runtime.h>

// SSIM fused kernel, round 5: R3 structure + packed-fp32 (v_pk_fma_f32) blur chains.
// B=16, C=3, H=W=768, 11-tap separable Gaussian, VALID -> 758x758; out = per-batch mean [16].
//
// vs R3 (180 us, the best round):
//  - Both blur stages packed: (x,y) chain and (x^2+y^2, x*y) chain as f32x2 pk_fma.
//    Per-component op order identical to R3 => expect bitwise-equal output.
//  - LDS stays field-major b32 ([row][field][col], float4 writes, stride-1 b32 reads):
//    R3 measured 0 bank conflicts; R2/R4 packed/b128 layouts measured 4.4M/13.3M.
//  - waves_per_eu(3,3) kept: R1/R2/R4 show any slack lets the allocator chase max
//    occupancy (64 VGPRs) and spill (R4: 52 MB scratch writes).
//  - Stage A pass-split (mu-chain -> LDS, square in place, sp-chain) to keep peak
//    live state ~140 < 168-VGPR budget.

typedef float f32x2 __attribute__((ext_vector_type(2)));

#define H_IMG 768
#define W_IMG 768
#define OH 758
#define OW_TOT 758
#define OWS 256   // output cols per strip
#define NSEG 16   // vertical segments

static __device__ __forceinline__ f32x2 mk2(float a, float b) {
    f32x2 r; r.x = a; r.y = b; return r;
}

__global__ void ssim_zero_out(float* __restrict__ out) {
    if (threadIdx.x < 16) out[threadIdx.x] = 0.0f;
}

__attribute__((amdgpu_flat_work_group_size(256, 256), amdgpu_waves_per_eu(3, 3)))
__global__ void ssim_fused(const float* __restrict__ X, const float* __restrict__ Y,
                           const float* __restrict__ Wg, float* __restrict__ out) {
    const float C1 = 1e-4f, C2 = 9e-4f, EPS = 1e-8f;
    const float INV_COUNT = 1.0f / (3.0f * 758.0f * 758.0f);

    const int t = threadIdx.x;
    int bx = blockIdx.x;
    const int seg = bx & (NSEG - 1); bx >>= 4;
    const int strip = bx % 3; bx /= 3;
    const int ch = bx % 3;
    const int b  = bx / 3;

    const int R0 = (OH * seg) / NSEG;
    const int Rend = (OH * (seg + 1)) / NSEG;
    const int hseg = Rend - R0;
    const int c0 = strip * OWS;

    const float* Xi = X + (size_t)(b * 3 + ch) * (H_IMG * W_IMG);
    const float* Yi = Y + (size_t)(b * 3 + ch) * (H_IMG * W_IMG);

    // Broadcast weights as packed pairs (pk_fma src).
    f32x2 ww[11];
#pragma unroll
    for (int k = 0; k < 11; ++k) { float wk = Wg[k]; ww[k] = mk2(wk, wk); }

    // LDS handoff: [4 stage-A rows][4 fields: mux,muy,sumsq,prod][256 cols]
    __shared__ float hb[4][4][OWS];   // 16 KB
    __shared__ float red[4];

    // Stage A mapping: 4 rows x 64 col-groups (4 cols each)
    const int sA = t >> 6;
    const int cg = t & 63;
    const int colbase = c0 + 4 * cg;
    const int k0 = min(colbase,      W_IMG - 4);
    const int k1 = min(colbase + 4,  W_IMG - 4);
    const int k2 = min(colbase + 8,  W_IMG - 4);
    const int k3 = min(colbase + 12, W_IMG - 2);

    // Stage B: packed ring-16. rg01 = (mu_x, mu_y), rg23 = (x2+y2, xy). Slot of rel row r = r & 15.
    f32x2 rg01[16], rg23[16];
#pragma unroll
    for (int j = 0; j < 16; ++j) { rg01[j] = mk2(0.f, 0.f); rg23[j] = mk2(0.f, 0.f); }

    const bool colok = (c0 + t) < OW_TOT;
    float local = 0.0f;
    const int M = (hseg + 13) >> 2;   // macro-iters of 4 input rows

    for (int mb = 0; mb < M; mb += 4) {
#pragma unroll
        for (int p = 0; p < 4; ++p) {
            const int m = mb + p;
            if (m < M) {
                // ---------------- Stage A: horizontal blur (packed, pass-split) ----------------
                {
                    int r = R0 + 4 * m + sA;
                    r = min(r, H_IMG - 1);
                    const float* xr = Xi + (size_t)r * W_IMG;
                    const float* yr = Yi + (size_t)r * W_IMG;
                    float4 xa = *(const float4*)(xr + k0);
                    float4 xb = *(const float4*)(xr + k1);
                    float4 xc = *(const float4*)(xr + k2);
                    float2 xd = *(const float2*)(xr + k3);
                    float4 ya = *(const float4*)(yr + k0);
                    float4 yb = *(const float4*)(yr + k1);
                    float4 yc = *(const float4*)(yr + k2);
                    float2 yd = *(const float2*)(yr + k3);
                    f32x2 v[14] = {
                        mk2(xa.x, ya.x), mk2(xa.y, ya.y), mk2(xa.z, ya.z), mk2(xa.w, ya.w),
                        mk2(xb.x, yb.x), mk2(xb.y, yb.y), mk2(xb.z, yb.z), mk2(xb.w, yb.w),
                        mk2(xc.x, yc.x), mk2(xc.y, yc.y), mk2(xc.z, yc.z), mk2(xc.w, yc.w),
                        mk2(xd.x, yd.x), mk2(xd.y, yd.y)};

                    // Pass 1: mu chain -> LDS fields 0,1.
                    {
                        f32x2 hm[4];
#pragma unroll
                        for (int cc = 0; cc < 4; ++cc) {
                            f32x2 a = mk2(0.f, 0.f);
#pragma unroll
                            for (int k = 0; k < 11; ++k)
                                a = __builtin_elementwise_fma(ww[k], v[cc + k], a);
                            hm[cc] = a;
                        }
                        *(float4*)&hb[sA][0][4 * cg] = make_float4(hm[0].x, hm[1].x, hm[2].x, hm[3].x);
                        *(float4*)&hb[sA][1][4 * cg] = make_float4(hm[0].y, hm[1].y, hm[2].y, hm[3].y);
                    }
                    // Square in place: v <- (x^2+y^2, x*y).
#pragma unroll
                    for (int j = 0; j < 14; ++j) {
                        const float xx = v[j].x, yy = v[j].y;
                        v[j] = mk2(fmaf(xx, xx, yy * yy), xx * yy);
                    }
                    // Pass 2: (sumsq, prod) chain -> LDS fields 2,3.
                    {
                        f32x2 hs[4];
#pragma unroll
                        for (int cc = 0; cc < 4; ++cc) {
                            f32x2 a = mk2(0.f, 0.f);
#pragma unroll
                            for (int k = 0; k < 11; ++k)
                                a = __builtin_elementwise_fma(ww[k], v[cc + k], a);
                            hs[cc] = a;
                        }
                        *(float4*)&hb[sA][2][4 * cg] = make_float4(hs[0].x, hs[1].x, hs[2].x, hs[3].x);
                        *(float4*)&hb[sA][3][4 * cg] = make_float4(hs[0].y, hs[1].y, hs[2].y, hs[3].y);
                    }
                }
                __syncthreads();

                // ---------------- Stage B: insert + vertical blur (packed) + SSIM ----------------
                {
                    // b32 stride-1 reads assembled straight into pair halves.
#pragma unroll
                    for (int s2 = 0; s2 < 4; ++s2) {
                        const int sl = (4 * p + s2) & 15;
                        rg01[sl] = mk2(hb[s2][0][t], hb[s2][1][t]);
                        rg23[sl] = mk2(hb[s2][2][t], hb[s2][3][t]);
                    }
#pragma unroll
                    for (int s2 = 0; s2 < 4; ++s2) {
                        const int orel = 4 * m - 10 + s2;
                        f32x2 a01 = mk2(0.f, 0.f), a23 = mk2(0.f, 0.f);
#pragma unroll
                        for (int k = 0; k < 11; ++k) {
                            const int sl = (4 * p + s2 + k + 6) & 15;
                            a01 = __builtin_elementwise_fma(ww[k], rg01[sl], a01);
                            a23 = __builtin_elementwise_fma(ww[k], rg23[sl], a23);
                        }
                        const float a0 = a01.x, a1 = a01.y, a2 = a23.x, a3 = a23.y;
                        const float mux2 = a0 * a0;
                        const float muy2 = a1 * a1;
                        const float mxy  = a0 * a1;
                        const float sigsum = a2 - mux2 - muy2;  // sigma_x + sigma_y
                        const float sxy    = a3 - mxy;
                        const float num = (2.0f * mxy + C1) * (2.0f * sxy + C2);
                        const float den = (mux2 + muy2 + C1 + EPS) * (sigsum + C2 + EPS);
                        const float v = fmaxf(__fdividef(num, den), 0.0f);
                        if (colok && (orel >= 0) && (orel < hseg)) local += v;
                    }
                }
                __syncthreads();
            }
        }
    }

    // ---------------- block reduction + atomic ----------------
    float v = local;
#pragma unroll
    for (int off = 32; off > 0; off >>= 1) v += __shfl_down(v, off, 64);
    if ((t & 63) == 0) red[t >> 6] = v;
    __syncthreads();
    if (t == 0) {
        atomicAdd(&out[b], (red[0] + red[1] + red[2] + red[3]) * INV_COUNT);
    }
}

extern "C" void kernel_launch(void* const* d_in, const int* in_sizes, int n_in,
                              void* d_out, int out_size, void* d_ws, size_t ws_size,
                              hipStream_t stream) {
    const float* X  = (const float*)d_in[0];
    const float* Y  = (const float*)d_in[1];
    const float* Wg = (const float*)d_in[2];
    float* out = (float*)d_out;

    hipLaunchKernelGGL(ssim_zero_out, dim3(1), dim3(64), 0, stream, out);
    hipLaunchKernelGGL(ssim_fused, dim3(16 * 3 * 3 * NSEG), dim3(256), 0, stream,
                       X, Y, Wg, out);
}